// Round 5
// baseline (12313.015 us; speedup 1.0000x reference)
//
#include <hip/hip_runtime.h>
#include <hip/hip_bf16.h>
#include <math.h>

constexpr int B = 64, N = 307, F = 64, T = 12, K = 3, C = 64, CT = 64;
constexpr float LN_EPS = 1e-5f;
constexpr int FT = F * T;  // 768

// ---------------- temporal attention ----------------

// lhs1_e[b,t,f] = sum_n x[b,n,f,t] * U1[n]
__global__ void k_lhs1_e(const float* __restrict__ x, const float* __restrict__ U1,
                         float* __restrict__ out) {
    int idx = blockIdx.x * blockDim.x + threadIdx.x;
    if (idx >= B * T * F) return;
    int f = idx % F;
    int t = (idx / F) % T;
    int b = idx / (F * T);
    const float* xp = x + ((size_t)b * N * F + f) * T + t;
    float s = 0.f;
    for (int n = 0; n < N; n++) s += xp[(size_t)n * F * T] * U1[n];
    out[idx] = s;
}

// rhs_e[b,n,t] = sum_f U3[f] * x[b,n,f,t]
__global__ void k_rhs_e(const float* __restrict__ x, const float* __restrict__ U3,
                        float* __restrict__ out) {
    int idx = blockIdx.x * blockDim.x + threadIdx.x;
    if (idx >= B * N * T) return;
    int t = idx % T;
    size_t bn = idx / T;
    const float* xp = x + bn * F * T + t;
    float s = 0.f;
    for (int f = 0; f < F; f++) s += U3[f] * xp[f * T];
    out[idx] = s;
}

// lhs_e[b,t,n] = sum_f lhs1_e[b,t,f] * U2[f,n]
__global__ void k_lhs_e(const float* __restrict__ lhs1, const float* __restrict__ U2,
                        float* __restrict__ out) {
    int idx = blockIdx.x * blockDim.x + threadIdx.x;
    if (idx >= B * T * N) return;
    int n = idx % N;
    int bt = idx / N;
    const float* lp = lhs1 + (size_t)bt * F;
    float s = 0.f;
    for (int f = 0; f < F; f++) s += lp[f] * U2[f * N + n];
    out[idx] = s;
}

// prod/sigmoid/V_e/softmax fused per batch: E[b,u,t] softmaxed over u
__global__ void k_tatt(const float* __restrict__ lhs, const float* __restrict__ rhs,
                       const float* __restrict__ b_e, const float* __restrict__ V_e,
                       float* __restrict__ E) {
    int b = blockIdx.x;
    int tid = threadIdx.x;
    __shared__ float sig[T * T];
    __shared__ float Ev[T * T];
    __shared__ float mx[T], sm[T];
    if (tid < T * T) {
        int t = tid % T, u = tid / T;
        const float* lp = lhs + ((size_t)b * T + u) * N;
        const float* rp = rhs + (size_t)b * N * T + t;
        float s = 0.f;
        for (int n = 0; n < N; n++) s += lp[n] * rp[(size_t)n * T];
        s += b_e[u * T + t];
        sig[tid] = 1.f / (1.f + expf(-s));
    }
    __syncthreads();
    if (tid < T * T) {
        int t = tid % T, u = tid / T;
        float e = 0.f;
        for (int v = 0; v < T; v++) e += V_e[u * T + v] * sig[v * T + t];
        Ev[tid] = e;
    }
    __syncthreads();
    if (tid < T) {
        float m = -1e30f;
        for (int u = 0; u < T; u++) m = fmaxf(m, Ev[u * T + tid]);
        float s = 0.f;
        for (int u = 0; u < T; u++) s += expf(Ev[u * T + tid] - m);
        mx[tid] = m;
        sm[tid] = s;
    }
    __syncthreads();
    if (tid < T * T) {
        int t = tid % T;
        E[(size_t)b * T * T + tid] = expf(Ev[tid] - mx[t]) / sm[t];
    }
}

// EW1[b,tp] = sum_t E[b,tp,t] * W1[t]
__global__ void k_EW1(const float* __restrict__ E, const float* __restrict__ W1,
                      float* __restrict__ out) {
    int idx = blockIdx.x * blockDim.x + threadIdx.x;
    if (idx >= B * T) return;
    const float* Ep = E + (size_t)idx * T;
    float s = 0.f;
    for (int t = 0; t < T; t++) s += Ep[t] * W1[t];
    out[idx] = s;
}

// ---------------- spatial attention (x_TAt folded in algebraically) ----------------

// lhs_s[b,n,t] = sum_f (sum_tp x[b,n,f,tp]*EW1[b,tp]) * W2[f,t]
__global__ void k_lhs_sf(const float* __restrict__ x, const float* __restrict__ EW1,
                         const float* __restrict__ W2, float* __restrict__ lhs_s) {
    int bn = blockIdx.x;
    int b = bn / N;
    int tid = threadIdx.x;  // 64
    __shared__ float a[F];
    __shared__ float ew[T];
    if (tid < T) ew[tid] = EW1[(size_t)b * T + tid];
    __syncthreads();
    const float* xp = x + (size_t)bn * F * T + tid * T;  // row f = tid
    float s = 0.f;
    for (int tp = 0; tp < T; tp++) s += xp[tp] * ew[tp];
    a[tid] = s;
    __syncthreads();
    if (tid < T) {
        float s2 = 0.f;
        for (int f = 0; f < F; f++) s2 += a[f] * W2[f * T + tid];
        lhs_s[(size_t)bn * T + tid] = s2;
    }
}

// xw3[b,m,tp] = sum_f W3[f] * x[b,m,f,tp]
__global__ void k_xw3(const float* __restrict__ x, const float* __restrict__ W3,
                      float* __restrict__ out) {
    int idx = blockIdx.x * blockDim.x + threadIdx.x;
    if (idx >= B * N * T) return;
    int tp = idx % T;
    size_t bm = idx / T;
    const float* xp = x + bm * F * T + tp;
    float s = 0.f;
    for (int f = 0; f < F; f++) s += W3[f] * xp[f * T];
    out[idx] = s;
}

// rhs_s[b,t,m] = sum_tp xw3[b,m,tp] * E[b,tp,t]
__global__ void k_rhs_s2(const float* __restrict__ xw3, const float* __restrict__ E,
                         float* __restrict__ out) {
    int idx = blockIdx.x * blockDim.x + threadIdx.x;
    if (idx >= B * T * N) return;
    int m = idx % N;
    int t = (idx / N) % T;
    int b = idx / (N * T);
    const float* xp = xw3 + ((size_t)b * N + m) * T;
    const float* Ep = E + (size_t)b * T * T + t;
    float s = 0.f;
    for (int tp = 0; tp < T; tp++) s += xp[tp] * Ep[tp * T];
    out[idx] = s;
}

// VsT[v,i] = V_s[i,v]
__global__ void k_transposeVs(const float* __restrict__ V, float* __restrict__ VT) {
    int idx = blockIdx.x * blockDim.x + threadIdx.x;
    if (idx >= N * N) return;
    int v = idx % N;
    int i = idx / N;
    VT[(size_t)v * N + i] = V[(size_t)i * N + v];
}

// fused sigmoid + V_s projection, AT=4 rows per block for VsT reuse
constexpr int AT = 4;
constexpr int NAB = (N + AT - 1) / AT;  // 77

__global__ void k_sigS(const float* __restrict__ lhs_s, const float* __restrict__ rhs_s,
                       const float* __restrict__ b_s, const float* __restrict__ VsT,
                       float* __restrict__ S) {
    int blk = blockIdx.x;
    int b = blk / NAB;
    int a0 = (blk % NAB) * AT;
    int tid = threadIdx.x;  // 256
    __shared__ float lrow[AT][T];
    __shared__ float sig4[AT][N];
    if (tid < AT * T) {
        int a = tid / T, t = tid % T;
        lrow[a][t] = (a0 + a < N) ? lhs_s[((size_t)b * N + a0 + a) * T + t] : 0.f;
    }
    __syncthreads();
    for (int v = tid; v < N; v += 256) {
        float rv[T];
        for (int t = 0; t < T; t++) rv[t] = rhs_s[((size_t)b * T + t) * N + v];
        for (int a = 0; a < AT; a++) {
            if (a0 + a >= N) break;
            float s = 0.f;
            for (int t = 0; t < T; t++) s += lrow[a][t] * rv[t];
            s += b_s[(size_t)(a0 + a) * N + v];
            sig4[a][v] = 1.f / (1.f + expf(-s));
        }
    }
    __syncthreads();
    for (int i = tid; i < N; i += 256) {
        float s[AT] = {0.f, 0.f, 0.f, 0.f};
        for (int v = 0; v < N; v++) {
            float vt = VsT[(size_t)v * N + i];
            for (int a = 0; a < AT; a++) s[a] += sig4[a][v] * vt;
        }
        for (int a = 0; a < AT; a++)
            if (a0 + a < N) S[((size_t)b * N + a0 + a) * N + i] = s[a];
    }
}

// softmax over a (axis 1) for each (b, i) — lanes span consecutive i => coalesced
__global__ void k_softmax_S(float* __restrict__ S) {
    int idx = blockIdx.x * blockDim.x + threadIdx.x;
    if (idx >= B * N) return;
    int b = idx / N;
    int i = idx % N;
    float* p = S + (size_t)b * N * N + i;
    float m = -1e30f;
    for (int a = 0; a < N; a++) m = fmaxf(m, p[(size_t)a * N]);
    float s = 0.f;
    for (int a = 0; a < N; a++) s += expf(p[(size_t)a * N] - m);
    float inv = 1.f / s;
    for (int a = 0; a < N; a++) p[(size_t)a * N] = expf(p[(size_t)a * N] - m) * inv;
}

// ---------------- chebyshev graph conv + Theta + relu -> sg (in d_out) ----------------
// z_k[b,j,f,t] = sum_i (cheb[k,i,j]*S[b,i,j]) * x[b,i,f,t]
// sg[b,j,c,t]  = relu( sum_k sum_f z_k * Theta[k,f,c] )

constexpr int JT = 8;
constexpr int NJB = (N + JT - 1) / JT;  // 39
constexpr int JH = JT / 2;              // 4 (zl processed in two halves)

__global__ void __launch_bounds__(256, 3)
k_gcnz(const float* __restrict__ x, const float* __restrict__ S,
       const float* __restrict__ cheb, const float* __restrict__ Theta,
       float* __restrict__ sg) {
    int blk = blockIdx.x;
    int b = blk / NJB;
    int j0 = (blk % NJB) * JT;
    int tid = threadIdx.x;  // 256

    __shared__ float wl[64][K * JT];  // 6 KB, [ii][k*JT+jj] contiguous per ii
    __shared__ float zl[K][JH][FT];   // 36 KB, half the j's at a time

    float acc[K][JT][3];
    for (int k = 0; k < K; k++)
        for (int jj = 0; jj < JT; jj++)
            for (int r = 0; r < 3; r++) acc[k][jj][r] = 0.f;

    const float* xb = x + (size_t)b * N * FT;

    for (int ic = 0; ic < N; ic += 64) {
        for (int l = tid; l < 64 * K * JT; l += 256) {
            int ii = l / (K * JT);
            int m = l % (K * JT);
            int k = m / JT, jj = m % JT;
            int i = ic + ii, j = j0 + jj;
            float w = 0.f;
            if (i < N && j < N)
                w = cheb[((size_t)k * N + i) * N + j] * S[((size_t)b * N + i) * N + j];
            wl[ii][m] = w;
        }
        __syncthreads();
        int imax = min(64, N - ic);
        for (int ii = 0; ii < imax; ii++) {
            float xv[3];
            const float* xr = xb + (size_t)(ic + ii) * FT;
#pragma unroll
            for (int r = 0; r < 3; r++) xv[r] = xr[tid + 256 * r];
#pragma unroll
            for (int k = 0; k < K; k++)
#pragma unroll
                for (int jj = 0; jj < JT; jj++) {
                    float w = wl[ii][k * JT + jj];
#pragma unroll
                    for (int r = 0; r < 3; r++) acc[k][jj][r] += w * xv[r];
                }
        }
        __syncthreads();
    }

    // Theta contraction in two jj-halves (zl LDS reused)
    for (int ph = 0; ph < 2; ph++) {
        for (int k = 0; k < K; k++)
            for (int jh = 0; jh < JH; jh++)
#pragma unroll
                for (int r = 0; r < 3; r++)
                    zl[k][jh][tid + 256 * r] = acc[k][ph * JH + jh][r];
        __syncthreads();
        for (int jh = 0; jh < JH; jh++) {
            int j = j0 + ph * JH + jh;
            if (j < N) {
                float* op = sg + ((size_t)b * N + j) * FT;
                for (int r = 0; r < 3; r++) {
                    int e = tid + 256 * r;  // c*T + t
                    int c = e / T;
                    int t = e % T;
                    float s = 0.f;
                    for (int k = 0; k < K; k++) {
                        const float* zp = &zl[k][jh][t];
                        const float* tp = Theta + (size_t)k * F * C + c;
                        for (int f = 0; f < F; f++) s += zp[f * T] * tp[f * C];
                    }
                    op[e] = fmaxf(s, 0.f);
                }
            }
        }
        __syncthreads();
    }
}

// ---------------- tconv + rconv + relu + LayerNorm (in-place on d_out) ----------------

__global__ void k_rest(const float* __restrict__ x,
                       const float* __restrict__ tw, const float* __restrict__ tb,
                       const float* __restrict__ rw, const float* __restrict__ rb,
                       const float* __restrict__ gamma, const float* __restrict__ beta,
                       float* __restrict__ io) {
    int bn = blockIdx.x;  // b*N + n
    int tid = threadIdx.x;  // 256
    __shared__ float xl[FT];   // x[f*T+t]
    __shared__ float sgl[FT];  // sg[c*T+t]
    __shared__ float hl[FT];   // h[ct*T+t]
    __shared__ float mu[T], rstd[T];
    const float* xp = x + (size_t)bn * FT;
    float* iop = io + (size_t)bn * FT;
    for (int l = tid; l < FT; l += 256) {
        xl[l] = xp[l];
        sgl[l] = iop[l];  // sg row (written by k_gcnz, already relu'd)
    }
    __syncthreads();
    for (int r = 0; r < 3; r++) {
        int e = tid + 256 * r;  // ct*T + t
        int ct = e / T;
        int t = e % T;
        float res = rb[ct];
        const float* rwp = rw + (size_t)ct * F;
        for (int f = 0; f < F; f++) res += xl[f * T + t] * rwp[f];
        float tco = tb[ct];
        const float* twp = tw + (size_t)ct * C * 3;
        for (int c = 0; c < C; c++) {
            float s0 = (t > 0) ? sgl[c * T + t - 1] : 0.f;
            float s1 = sgl[c * T + t];
            float s2 = (t < T - 1) ? sgl[c * T + t + 1] : 0.f;
            tco += s0 * twp[c * 3 + 0] + s1 * twp[c * 3 + 1] + s2 * twp[c * 3 + 2];
        }
        hl[e] = fmaxf(res + tco, 0.f);
    }
    __syncthreads();
    if (tid < T) {
        float m = 0.f;
        for (int ct = 0; ct < CT; ct++) m += hl[ct * T + tid];
        m /= CT;
        float v = 0.f;
        for (int ct = 0; ct < CT; ct++) {
            float d = hl[ct * T + tid] - m;
            v += d * d;
        }
        v /= CT;
        mu[tid] = m;
        rstd[tid] = rsqrtf(v + LN_EPS);
    }
    __syncthreads();
    for (int r = 0; r < 3; r++) {
        int e = tid + 256 * r;
        int ct = e / T;
        int t = e % T;
        iop[e] = (hl[e] - mu[t]) * rstd[t] * gamma[ct] + beta[ct];
    }
}

// ---------------- launch ----------------

extern "C" void kernel_launch(void* const* d_in, const int* in_sizes, int n_in,
                              void* d_out, int out_size, void* d_ws, size_t ws_size,
                              hipStream_t stream) {
    const float* x     = (const float*)d_in[0];
    const float* W1    = (const float*)d_in[1];
    const float* W2    = (const float*)d_in[2];
    const float* W3    = (const float*)d_in[3];
    const float* b_s   = (const float*)d_in[4];
    const float* V_s   = (const float*)d_in[5];
    const float* U1    = (const float*)d_in[6];
    const float* U2    = (const float*)d_in[7];
    const float* U3    = (const float*)d_in[8];
    const float* b_e   = (const float*)d_in[9];
    const float* V_e   = (const float*)d_in[10];
    const float* cheb  = (const float*)d_in[11];
    const float* Theta = (const float*)d_in[12];
    const float* tw    = (const float*)d_in[13];
    const float* tb    = (const float*)d_in[14];
    const float* rw    = (const float*)d_in[15];
    const float* rb    = (const float*)d_in[16];
    const float* gam   = (const float*)d_in[17];
    const float* bet   = (const float*)d_in[18];
    float* out = (float*)d_out;

    // workspace (floats): ~7.36 M floats = ~29.5 MB (sg lives in d_out)
    float* ws = (float*)d_ws;
    size_t off = 0;
    auto alloc = [&](size_t n) { float* p = ws + off; off += n; return p; };
    float* Sb     = alloc((size_t)B * N * N);
    float* VsT    = alloc((size_t)N * N);
    float* lhs1_e = alloc((size_t)B * T * F);
    float* lhs_e  = alloc((size_t)B * T * N);
    float* rhs_e  = alloc((size_t)B * N * T);
    float* Ebuf   = alloc((size_t)B * T * T);
    float* EW1    = alloc((size_t)B * T);
    float* xw3    = alloc((size_t)B * N * T);
    float* lhs_s  = alloc((size_t)B * N * T);
    float* rhs_s  = alloc((size_t)B * T * N);

    auto g = [](long n) { return dim3((unsigned)((n + 255) / 256)); };

    // temporal attention
    k_lhs1_e<<<g((long)B * T * F), 256, 0, stream>>>(x, U1, lhs1_e);
    k_rhs_e<<<g((long)B * N * T), 256, 0, stream>>>(x, U3, rhs_e);
    k_lhs_e<<<g((long)B * T * N), 256, 0, stream>>>(lhs1_e, U2, lhs_e);
    k_tatt<<<B, 256, 0, stream>>>(lhs_e, rhs_e, b_e, V_e, Ebuf);

    // spatial attention (x_TAt folded in)
    k_EW1<<<g((long)B * T), 256, 0, stream>>>(Ebuf, W1, EW1);
    k_lhs_sf<<<B * N, 64, 0, stream>>>(x, EW1, W2, lhs_s);
    k_xw3<<<g((long)B * N * T), 256, 0, stream>>>(x, W3, xw3);
    k_rhs_s2<<<g((long)B * T * N), 256, 0, stream>>>(xw3, Ebuf, rhs_s);
    k_transposeVs<<<g((long)N * N), 256, 0, stream>>>(V_s, VsT);
    k_sigS<<<B * NAB, 256, 0, stream>>>(lhs_s, rhs_s, b_s, VsT, Sb);
    k_softmax_S<<<g((long)B * N), 256, 0, stream>>>(Sb);

    // graph conv + Theta + relu -> sg staged in d_out
    k_gcnz<<<B * NJB, 256, 0, stream>>>(x, Sb, cheb, Theta, out);

    // tconv + rconv + relu + LN, in-place on d_out (each block owns its row)
    k_rest<<<B * N, 256, 0, stream>>>(x, tw, tb, rw, rb, gam, bet, out);
}

// Round 6
// 2456.534 us; speedup vs baseline: 5.0124x; 5.0124x over previous
//
#include <hip/hip_runtime.h>
#include <hip/hip_bf16.h>
#include <math.h>

constexpr int B = 64, N = 307, F = 64, T = 12, K = 3, C = 64, CT = 64;
constexpr float LN_EPS = 1e-5f;
constexpr int FT = F * T;  // 768

// ---------------- temporal attention ----------------

// lhs1_e[b,t,f] = sum_n x[b,n,f,t] * U1[n]
__global__ void k_lhs1_e(const float* __restrict__ x, const float* __restrict__ U1,
                         float* __restrict__ out) {
    int idx = blockIdx.x * blockDim.x + threadIdx.x;
    if (idx >= B * T * F) return;
    int f = idx % F;
    int t = (idx / F) % T;
    int b = idx / (F * T);
    const float* xp = x + ((size_t)b * N * F + f) * T + t;
    float s = 0.f;
    for (int n = 0; n < N; n++) s += xp[(size_t)n * F * T] * U1[n];
    out[idx] = s;
}

// fused: rhs_e[b,n,t] = sum_f U3[f]*x[b,n,f,t];  xw3[b,n,t] = sum_f W3[f]*x[b,n,f,t]
__global__ void k_xdots(const float* __restrict__ x, const float* __restrict__ U3,
                        const float* __restrict__ W3, float* __restrict__ rhs_e,
                        float* __restrict__ xw3) {
    int idx = blockIdx.x * blockDim.x + threadIdx.x;
    if (idx >= B * N * T) return;
    int t = idx % T;
    size_t bn = idx / T;
    const float* xp = x + bn * F * T + t;
    float s1 = 0.f, s2 = 0.f;
    for (int f = 0; f < F; f++) {
        float v = xp[f * T];
        s1 += U3[f] * v;
        s2 += W3[f] * v;
    }
    rhs_e[idx] = s1;
    xw3[idx] = s2;
}

// lhs_e[b,t,n] = sum_f lhs1_e[b,t,f] * U2[f,n]
__global__ void k_lhs_e(const float* __restrict__ lhs1, const float* __restrict__ U2,
                        float* __restrict__ out) {
    int idx = blockIdx.x * blockDim.x + threadIdx.x;
    if (idx >= B * T * N) return;
    int n = idx % N;
    int bt = idx / N;
    const float* lp = lhs1 + (size_t)bt * F;
    float s = 0.f;
    for (int f = 0; f < F; f++) s += lp[f] * U2[f * N + n];
    out[idx] = s;
}

// prod/sigmoid/V_e/softmax fused per batch: E[b,u,t] softmaxed over u
__global__ void k_tatt(const float* __restrict__ lhs, const float* __restrict__ rhs,
                       const float* __restrict__ b_e, const float* __restrict__ V_e,
                       float* __restrict__ E) {
    int b = blockIdx.x;
    int tid = threadIdx.x;
    __shared__ float sig[T * T];
    __shared__ float Ev[T * T];
    __shared__ float mx[T], sm[T];
    if (tid < T * T) {
        int t = tid % T, u = tid / T;
        const float* lp = lhs + ((size_t)b * T + u) * N;
        const float* rp = rhs + (size_t)b * N * T + t;
        float s = 0.f;
        for (int n = 0; n < N; n++) s += lp[n] * rp[(size_t)n * T];
        s += b_e[u * T + t];
        sig[tid] = 1.f / (1.f + expf(-s));
    }
    __syncthreads();
    if (tid < T * T) {
        int t = tid % T, u = tid / T;
        float e = 0.f;
        for (int v = 0; v < T; v++) e += V_e[u * T + v] * sig[v * T + t];
        Ev[tid] = e;
    }
    __syncthreads();
    if (tid < T) {
        float m = -1e30f;
        for (int u = 0; u < T; u++) m = fmaxf(m, Ev[u * T + tid]);
        float s = 0.f;
        for (int u = 0; u < T; u++) s += expf(Ev[u * T + tid] - m);
        mx[tid] = m;
        sm[tid] = s;
    }
    __syncthreads();
    if (tid < T * T) {
        int t = tid % T;
        E[(size_t)b * T * T + tid] = expf(Ev[tid] - mx[t]) / sm[t];
    }
}

// EW1[b,tp] = sum_t E[b,tp,t] * W1[t]
__global__ void k_EW1(const float* __restrict__ E, const float* __restrict__ W1,
                      float* __restrict__ out) {
    int idx = blockIdx.x * blockDim.x + threadIdx.x;
    if (idx >= B * T) return;
    const float* Ep = E + (size_t)idx * T;
    float s = 0.f;
    for (int t = 0; t < T; t++) s += Ep[t] * W1[t];
    out[idx] = s;
}

// ---------------- spatial attention (x_TAt folded in algebraically) ----------------

// lhs_s[b,n,t] = sum_f (sum_tp x[b,n,f,tp]*EW1[b,tp]) * W2[f,t]
__global__ void k_lhs_sf(const float* __restrict__ x, const float* __restrict__ EW1,
                         const float* __restrict__ W2, float* __restrict__ lhs_s) {
    int bn = blockIdx.x;
    int b = bn / N;
    int tid = threadIdx.x;  // 64
    __shared__ float a[F];
    __shared__ float ew[T];
    if (tid < T) ew[tid] = EW1[(size_t)b * T + tid];
    __syncthreads();
    const float* xp = x + (size_t)bn * F * T + tid * T;  // row f = tid
    float s = 0.f;
    for (int tp = 0; tp < T; tp++) s += xp[tp] * ew[tp];
    a[tid] = s;
    __syncthreads();
    if (tid < T) {
        float s2 = 0.f;
        for (int f = 0; f < F; f++) s2 += a[f] * W2[f * T + tid];
        lhs_s[(size_t)bn * T + tid] = s2;
    }
}

// rhs_s[b,t,m] = sum_tp xw3[b,m,tp] * E[b,tp,t]
__global__ void k_rhs_s2(const float* __restrict__ xw3, const float* __restrict__ E,
                         float* __restrict__ out) {
    int idx = blockIdx.x * blockDim.x + threadIdx.x;
    if (idx >= B * T * N) return;
    int m = idx % N;
    int t = (idx / N) % T;
    int b = idx / (N * T);
    const float* xp = xw3 + ((size_t)b * N + m) * T;
    const float* Ep = E + (size_t)b * T * T + t;
    float s = 0.f;
    for (int tp = 0; tp < T; tp++) s += xp[tp] * Ep[tp * T];
    out[idx] = s;
}

// VsT[v,i] = V_s[i,v]
__global__ void k_transposeVs(const float* __restrict__ V, float* __restrict__ VT) {
    int idx = blockIdx.x * blockDim.x + threadIdx.x;
    if (idx >= N * N) return;
    int v = idx % N;
    int i = idx / N;
    VT[(size_t)v * N + i] = V[(size_t)i * N + v];
}

// fused sigmoid + V_s projection, AT=4 rows per block for VsT reuse
constexpr int AT = 4;
constexpr int NAB = (N + AT - 1) / AT;  // 77

__global__ void k_sigS(const float* __restrict__ lhs_s, const float* __restrict__ rhs_s,
                       const float* __restrict__ b_s, const float* __restrict__ VsT,
                       float* __restrict__ S) {
    int blk = blockIdx.x;
    int b = blk / NAB;
    int a0 = (blk % NAB) * AT;
    int tid = threadIdx.x;  // 256
    __shared__ float lrow[AT][T];
    __shared__ float sig4[AT][N];
    if (tid < AT * T) {
        int a = tid / T, t = tid % T;
        lrow[a][t] = (a0 + a < N) ? lhs_s[((size_t)b * N + a0 + a) * T + t] : 0.f;
    }
    __syncthreads();
    for (int v = tid; v < N; v += 256) {
        float rv[T];
        for (int t = 0; t < T; t++) rv[t] = rhs_s[((size_t)b * T + t) * N + v];
        for (int a = 0; a < AT; a++) {
            if (a0 + a >= N) break;
            float s = 0.f;
            for (int t = 0; t < T; t++) s += lrow[a][t] * rv[t];
            s += b_s[(size_t)(a0 + a) * N + v];
            sig4[a][v] = 1.f / (1.f + expf(-s));
        }
    }
    __syncthreads();
    for (int i = tid; i < N; i += 256) {
        float s[AT] = {0.f, 0.f, 0.f, 0.f};
        for (int v = 0; v < N; v++) {
            float vt = VsT[(size_t)v * N + i];
            for (int a = 0; a < AT; a++) s[a] += sig4[a][v] * vt;
        }
        for (int a = 0; a < AT; a++)
            if (a0 + a < N) S[((size_t)b * N + a0 + a) * N + i] = s[a];
    }
}

// softmax over a (axis 1) for each (b, i) — lanes span consecutive i => coalesced
__global__ void k_softmax_S(float* __restrict__ S) {
    int idx = blockIdx.x * blockDim.x + threadIdx.x;
    if (idx >= B * N) return;
    int b = idx / N;
    int i = idx % N;
    float* p = S + (size_t)b * N * N + i;
    float m = -1e30f;
    for (int a = 0; a < N; a++) m = fmaxf(m, p[(size_t)a * N]);
    float s = 0.f;
    for (int a = 0; a < N; a++) s += expf(p[(size_t)a * N] - m);
    float inv = 1.f / s;
    for (int a = 0; a < N; a++) p[(size_t)a * N] = expf(p[(size_t)a * N] - m) * inv;
}

// ---------------- chebyshev graph conv + Theta + relu -> sg (in d_out) ----------------
// z_k[b,j,f,t] = sum_i (cheb[k,i,j]*S[b,i,j]) * x[b,i,f,t]
// sg[b,j,c,t]  = relu( sum_k sum_f z_k * Theta[k,f,c] )
// JT=4: acc = 36 floats/thread — MUST stay in VGPRs (JT=8 spilled: r5 post-mortem).
// No __launch_bounds__: capping waves/EU at 3 caused the r5 scratch spill.

constexpr int JT = 4;
constexpr int NJB = (N + JT - 1) / JT;  // 77

__global__ void k_gcnz(const float* __restrict__ x, const float* __restrict__ S,
                       const float* __restrict__ cheb, const float* __restrict__ Theta,
                       float* __restrict__ sg) {
    int blk = blockIdx.x;
    int b = blk / NJB;
    int j0 = (blk % NJB) * JT;
    int tid = threadIdx.x;  // 256

    __shared__ float wl[64][K * JT];  // 3 KB, [ii][k*JT+jj]
    __shared__ float zl[K][JT][FT];   // 36 KB

    float acc[K][JT][3];
#pragma unroll
    for (int k = 0; k < K; k++)
#pragma unroll
        for (int jj = 0; jj < JT; jj++)
#pragma unroll
            for (int r = 0; r < 3; r++) acc[k][jj][r] = 0.f;

    const float* xb = x + (size_t)b * N * FT;

    for (int ic = 0; ic < N; ic += 64) {
        for (int l = tid; l < 64 * K * JT; l += 256) {
            int ii = l / (K * JT);
            int m = l % (K * JT);
            int k = m / JT, jj = m % JT;
            int i = ic + ii, j = j0 + jj;
            float w = 0.f;
            if (i < N && j < N)
                w = cheb[((size_t)k * N + i) * N + j] * S[((size_t)b * N + i) * N + j];
            wl[ii][m] = w;
        }
        __syncthreads();
        int imax = min(64, N - ic);
        for (int ii = 0; ii < imax; ii++) {
            float xv[3];
            const float* xr = xb + (size_t)(ic + ii) * FT;
#pragma unroll
            for (int r = 0; r < 3; r++) xv[r] = xr[tid + 256 * r];
#pragma unroll
            for (int k = 0; k < K; k++)
#pragma unroll
                for (int jj = 0; jj < JT; jj++) {
                    float w = wl[ii][k * JT + jj];
#pragma unroll
                    for (int r = 0; r < 3; r++) acc[k][jj][r] += w * xv[r];
                }
        }
        __syncthreads();
    }

    // z -> LDS
#pragma unroll
    for (int k = 0; k < K; k++)
#pragma unroll
        for (int jj = 0; jj < JT; jj++)
#pragma unroll
            for (int r = 0; r < 3; r++) zl[k][jj][tid + 256 * r] = acc[k][jj][r];
    __syncthreads();

    // Theta contraction + relu; each Theta value reused across JT j's
    for (int r = 0; r < 3; r++) {
        int e = tid + 256 * r;  // c*T + t
        int c = e / T;
        int t = e % T;
        float s[JT] = {0.f, 0.f, 0.f, 0.f};
        for (int k = 0; k < K; k++) {
            const float* tp = Theta + (size_t)k * F * C + c;
            const float* zp = &zl[k][0][t];
#pragma unroll 4
            for (int f = 0; f < F; f++) {
                float tv = tp[f * C];
#pragma unroll
                for (int jj = 0; jj < JT; jj++) s[jj] += zp[jj * FT + f * T] * tv;
            }
        }
#pragma unroll
        for (int jj = 0; jj < JT; jj++) {
            int j = j0 + jj;
            if (j < N) sg[((size_t)b * N + j) * FT + e] = fmaxf(s[jj], 0.f);
        }
    }
}

// ---------------- tconv + rconv + relu + LayerNorm (in-place on d_out) ----------------

__global__ void k_rest(const float* __restrict__ x,
                       const float* __restrict__ tw, const float* __restrict__ tb,
                       const float* __restrict__ rw, const float* __restrict__ rb,
                       const float* __restrict__ gamma, const float* __restrict__ beta,
                       float* __restrict__ io) {
    int bn = blockIdx.x;  // b*N + n
    int tid = threadIdx.x;  // 256
    __shared__ float xl[FT];   // x[f*T+t]
    __shared__ float sgl[FT];  // sg[c*T+t]
    __shared__ float hl[FT];   // h[ct*T+t]
    __shared__ float mu[T], rstd[T];
    const float* xp = x + (size_t)bn * FT;
    float* iop = io + (size_t)bn * FT;
    for (int l = tid; l < FT; l += 256) {
        xl[l] = xp[l];
        sgl[l] = iop[l];  // sg row (written by k_gcnz, already relu'd)
    }
    __syncthreads();
    for (int r = 0; r < 3; r++) {
        int e = tid + 256 * r;  // ct*T + t
        int ct = e / T;
        int t = e % T;
        float res = rb[ct];
        const float* rwp = rw + (size_t)ct * F;
        for (int f = 0; f < F; f++) res += xl[f * T + t] * rwp[f];
        float tco = tb[ct];
        const float* twp = tw + (size_t)ct * C * 3;
        for (int c = 0; c < C; c++) {
            float s0 = (t > 0) ? sgl[c * T + t - 1] : 0.f;
            float s1 = sgl[c * T + t];
            float s2 = (t < T - 1) ? sgl[c * T + t + 1] : 0.f;
            tco += s0 * twp[c * 3 + 0] + s1 * twp[c * 3 + 1] + s2 * twp[c * 3 + 2];
        }
        hl[e] = fmaxf(res + tco, 0.f);
    }
    __syncthreads();
    if (tid < T) {
        float m = 0.f;
        for (int ct = 0; ct < CT; ct++) m += hl[ct * T + tid];
        m /= CT;
        float v = 0.f;
        for (int ct = 0; ct < CT; ct++) {
            float d = hl[ct * T + tid] - m;
            v += d * d;
        }
        v /= CT;
        mu[tid] = m;
        rstd[tid] = rsqrtf(v + LN_EPS);
    }
    __syncthreads();
    for (int r = 0; r < 3; r++) {
        int e = tid + 256 * r;
        int ct = e / T;
        int t = e % T;
        iop[e] = (hl[e] - mu[t]) * rstd[t] * gamma[ct] + beta[ct];
    }
}

// ---------------- launch ----------------

extern "C" void kernel_launch(void* const* d_in, const int* in_sizes, int n_in,
                              void* d_out, int out_size, void* d_ws, size_t ws_size,
                              hipStream_t stream) {
    const float* x     = (const float*)d_in[0];
    const float* W1    = (const float*)d_in[1];
    const float* W2    = (const float*)d_in[2];
    const float* W3    = (const float*)d_in[3];
    const float* b_s   = (const float*)d_in[4];
    const float* V_s   = (const float*)d_in[5];
    const float* U1    = (const float*)d_in[6];
    const float* U2    = (const float*)d_in[7];
    const float* U3    = (const float*)d_in[8];
    const float* b_e   = (const float*)d_in[9];
    const float* V_e   = (const float*)d_in[10];
    const float* cheb  = (const float*)d_in[11];
    const float* Theta = (const float*)d_in[12];
    const float* tw    = (const float*)d_in[13];
    const float* tb    = (const float*)d_in[14];
    const float* rw    = (const float*)d_in[15];
    const float* rb    = (const float*)d_in[16];
    const float* gam   = (const float*)d_in[17];
    const float* bet   = (const float*)d_in[18];
    float* out = (float*)d_out;

    // workspace (floats): ~7.36 M floats = ~29.5 MB (sg lives in d_out)
    float* ws = (float*)d_ws;
    size_t off = 0;
    auto alloc = [&](size_t n) { float* p = ws + off; off += n; return p; };
    float* Sb     = alloc((size_t)B * N * N);
    float* VsT    = alloc((size_t)N * N);
    float* lhs1_e = alloc((size_t)B * T * F);
    float* lhs_e  = alloc((size_t)B * T * N);
    float* rhs_e  = alloc((size_t)B * N * T);
    float* Ebuf   = alloc((size_t)B * T * T);
    float* EW1    = alloc((size_t)B * T);
    float* xw3    = alloc((size_t)B * N * T);
    float* lhs_s  = alloc((size_t)B * N * T);
    float* rhs_s  = alloc((size_t)B * T * N);

    auto g = [](long n) { return dim3((unsigned)((n + 255) / 256)); };

    // temporal attention (k_xdots also precomputes xw3 for spatial attention)
    k_lhs1_e<<<g((long)B * T * F), 256, 0, stream>>>(x, U1, lhs1_e);
    k_xdots<<<g((long)B * N * T), 256, 0, stream>>>(x, U3, W3, rhs_e, xw3);
    k_lhs_e<<<g((long)B * T * N), 256, 0, stream>>>(lhs1_e, U2, lhs_e);
    k_tatt<<<B, 256, 0, stream>>>(lhs_e, rhs_e, b_e, V_e, Ebuf);

    // spatial attention (x_TAt folded in)
    k_EW1<<<g((long)B * T), 256, 0, stream>>>(Ebuf, W1, EW1);
    k_lhs_sf<<<B * N, 64, 0, stream>>>(x, EW1, W2, lhs_s);
    k_rhs_s2<<<g((long)B * T * N), 256, 0, stream>>>(xw3, Ebuf, rhs_s);
    k_transposeVs<<<g((long)N * N), 256, 0, stream>>>(V_s, VsT);
    k_sigS<<<B * NAB, 256, 0, stream>>>(lhs_s, rhs_s, b_s, VsT, Sb);
    k_softmax_S<<<g((long)B * N), 256, 0, stream>>>(Sb);

    // graph conv + Theta + relu -> sg staged in d_out
    k_gcnz<<<B * NJB, 256, 0, stream>>>(x, Sb, cheb, Theta, out);

    // tconv + rconv + relu + LN, in-place on d_out (each block owns its row)
    k_rest<<<B * N, 256, 0, stream>>>(x, tw, tb, rw, rb, gam, bet, out);
}

// Round 7
// 1713.418 us; speedup vs baseline: 7.1862x; 1.4337x over previous
//
#include <hip/hip_runtime.h>
#include <hip/hip_bf16.h>
#include <math.h>

constexpr int B = 64, N = 307, F = 64, T = 12, K = 3, C = 64, CT = 64;
constexpr float LN_EPS = 1e-5f;
constexpr int FT = F * T;  // 768

// ---------------- temporal attention ----------------

// lhs1_e[b,t,f] = sum_n x[b,n,f,t] * U1[n]
__global__ void k_lhs1_e(const float* __restrict__ x, const float* __restrict__ U1,
                         float* __restrict__ out) {
    int idx = blockIdx.x * blockDim.x + threadIdx.x;
    if (idx >= B * T * F) return;
    int f = idx % F;
    int t = (idx / F) % T;
    int b = idx / (F * T);
    const float* xp = x + ((size_t)b * N * F + f) * T + t;
    float s = 0.f;
    for (int n = 0; n < N; n++) s += xp[(size_t)n * F * T] * U1[n];
    out[idx] = s;
}

// fused: rhs_e[b,n,t] = sum_f U3[f]*x[b,n,f,t];  xw3[b,n,t] = sum_f W3[f]*x[b,n,f,t]
__global__ void k_xdots(const float* __restrict__ x, const float* __restrict__ U3,
                        const float* __restrict__ W3, float* __restrict__ rhs_e,
                        float* __restrict__ xw3) {
    int idx = blockIdx.x * blockDim.x + threadIdx.x;
    if (idx >= B * N * T) return;
    int t = idx % T;
    size_t bn = idx / T;
    const float* xp = x + bn * F * T + t;
    float s1 = 0.f, s2 = 0.f;
    for (int f = 0; f < F; f++) {
        float v = xp[f * T];
        s1 += U3[f] * v;
        s2 += W3[f] * v;
    }
    rhs_e[idx] = s1;
    xw3[idx] = s2;
}

// lhs_e[b,t,n] = sum_f lhs1_e[b,t,f] * U2[f,n]
__global__ void k_lhs_e(const float* __restrict__ lhs1, const float* __restrict__ U2,
                        float* __restrict__ out) {
    int idx = blockIdx.x * blockDim.x + threadIdx.x;
    if (idx >= B * T * N) return;
    int n = idx % N;
    int bt = idx / N;
    const float* lp = lhs1 + (size_t)bt * F;
    float s = 0.f;
    for (int f = 0; f < F; f++) s += lp[f] * U2[f * N + n];
    out[idx] = s;
}

// prod/sigmoid/V_e/softmax fused per batch: E[b,u,t] softmaxed over u
__global__ void k_tatt(const float* __restrict__ lhs, const float* __restrict__ rhs,
                       const float* __restrict__ b_e, const float* __restrict__ V_e,
                       float* __restrict__ E) {
    int b = blockIdx.x;
    int tid = threadIdx.x;
    __shared__ float sig[T * T];
    __shared__ float Ev[T * T];
    __shared__ float mx[T], sm[T];
    if (tid < T * T) {
        int t = tid % T, u = tid / T;
        const float* lp = lhs + ((size_t)b * T + u) * N;
        const float* rp = rhs + (size_t)b * N * T + t;
        float s = 0.f;
        for (int n = 0; n < N; n++) s += lp[n] * rp[(size_t)n * T];
        s += b_e[u * T + t];
        sig[tid] = 1.f / (1.f + expf(-s));
    }
    __syncthreads();
    if (tid < T * T) {
        int t = tid % T, u = tid / T;
        float e = 0.f;
        for (int v = 0; v < T; v++) e += V_e[u * T + v] * sig[v * T + t];
        Ev[tid] = e;
    }
    __syncthreads();
    if (tid < T) {
        float m = -1e30f;
        for (int u = 0; u < T; u++) m = fmaxf(m, Ev[u * T + tid]);
        float s = 0.f;
        for (int u = 0; u < T; u++) s += expf(Ev[u * T + tid] - m);
        mx[tid] = m;
        sm[tid] = s;
    }
    __syncthreads();
    if (tid < T * T) {
        int t = tid % T;
        E[(size_t)b * T * T + tid] = expf(Ev[tid] - mx[t]) / sm[t];
    }
}

// EW1[b,tp] = sum_t E[b,tp,t] * W1[t]
__global__ void k_EW1(const float* __restrict__ E, const float* __restrict__ W1,
                      float* __restrict__ out) {
    int idx = blockIdx.x * blockDim.x + threadIdx.x;
    if (idx >= B * T) return;
    const float* Ep = E + (size_t)idx * T;
    float s = 0.f;
    for (int t = 0; t < T; t++) s += Ep[t] * W1[t];
    out[idx] = s;
}

// ---------------- spatial attention (x_TAt folded in algebraically) ----------------

// lhs_s[b,n,t] = sum_f (sum_tp x[b,n,f,tp]*EW1[b,tp]) * W2[f,t]
__global__ void k_lhs_sf(const float* __restrict__ x, const float* __restrict__ EW1,
                         const float* __restrict__ W2, float* __restrict__ lhs_s) {
    int bn = blockIdx.x;
    int b = bn / N;
    int tid = threadIdx.x;  // 64
    __shared__ float a[F];
    __shared__ float ew[T];
    if (tid < T) ew[tid] = EW1[(size_t)b * T + tid];
    __syncthreads();
    const float* xp = x + (size_t)bn * F * T + tid * T;  // row f = tid
    float s = 0.f;
    for (int tp = 0; tp < T; tp++) s += xp[tp] * ew[tp];
    a[tid] = s;
    __syncthreads();
    if (tid < T) {
        float s2 = 0.f;
        for (int f = 0; f < F; f++) s2 += a[f] * W2[f * T + tid];
        lhs_s[(size_t)bn * T + tid] = s2;
    }
}

// rhs_s[b,t,m] = sum_tp xw3[b,m,tp] * E[b,tp,t]
__global__ void k_rhs_s2(const float* __restrict__ xw3, const float* __restrict__ E,
                         float* __restrict__ out) {
    int idx = blockIdx.x * blockDim.x + threadIdx.x;
    if (idx >= B * T * N) return;
    int m = idx % N;
    int t = (idx / N) % T;
    int b = idx / (N * T);
    const float* xp = xw3 + ((size_t)b * N + m) * T;
    const float* Ep = E + (size_t)b * T * T + t;
    float s = 0.f;
    for (int tp = 0; tp < T; tp++) s += xp[tp] * Ep[tp * T];
    out[idx] = s;
}

// VsT[v,i] = V_s[i,v]
__global__ void k_transposeVs(const float* __restrict__ V, float* __restrict__ VT) {
    int idx = blockIdx.x * blockDim.x + threadIdx.x;
    if (idx >= N * N) return;
    int v = idx % N;
    int i = idx / N;
    VT[(size_t)v * N + i] = V[(size_t)i * N + v];
}

// twT[dt][ct][c] = tw[ct][c][dt]  (contiguous-c for float4 loads in k_rest)
__global__ void k_twT(const float* __restrict__ tw, float* __restrict__ twT) {
    int idx = blockIdx.x * blockDim.x + threadIdx.x;
    if (idx >= CT * C * 3) return;
    int dt = idx % 3;
    int c = (idx / 3) % C;
    int ct = idx / (3 * C);
    twT[((size_t)dt * CT + ct) * C + c] = tw[idx];
}

// fused sigmoid + V_s projection, AT=4 rows per block for VsT reuse
constexpr int AT = 4;
constexpr int NAB = (N + AT - 1) / AT;  // 77

__global__ void k_sigS(const float* __restrict__ lhs_s, const float* __restrict__ rhs_s,
                       const float* __restrict__ b_s, const float* __restrict__ VsT,
                       float* __restrict__ S) {
    int blk = blockIdx.x;
    int b = blk / NAB;
    int a0 = (blk % NAB) * AT;
    int tid = threadIdx.x;  // 256
    __shared__ float lrow[AT][T];
    __shared__ float sig4[AT][N];
    if (tid < AT * T) {
        int a = tid / T, t = tid % T;
        lrow[a][t] = (a0 + a < N) ? lhs_s[((size_t)b * N + a0 + a) * T + t] : 0.f;
    }
    __syncthreads();
    for (int v = tid; v < N; v += 256) {
        float rv[T];
        for (int t = 0; t < T; t++) rv[t] = rhs_s[((size_t)b * T + t) * N + v];
        for (int a = 0; a < AT; a++) {
            if (a0 + a >= N) break;
            float s = 0.f;
            for (int t = 0; t < T; t++) s += lrow[a][t] * rv[t];
            s += b_s[(size_t)(a0 + a) * N + v];
            sig4[a][v] = 1.f / (1.f + expf(-s));
        }
    }
    __syncthreads();
    for (int i = tid; i < N; i += 256) {
        float s[AT] = {0.f, 0.f, 0.f, 0.f};
        for (int v = 0; v < N; v++) {
            float vt = VsT[(size_t)v * N + i];
            for (int a = 0; a < AT; a++) s[a] += sig4[a][v] * vt;
        }
        for (int a = 0; a < AT; a++)
            if (a0 + a < N) S[((size_t)b * N + a0 + a) * N + i] = s[a];
    }
}

// softmax over a (axis 1) for each (b, i) — lanes span consecutive i => coalesced
__global__ void k_softmax_S(float* __restrict__ S) {
    int idx = blockIdx.x * blockDim.x + threadIdx.x;
    if (idx >= B * N) return;
    int b = idx / N;
    int i = idx % N;
    float* p = S + (size_t)b * N * N + i;
    float m = -1e30f;
    for (int a = 0; a < N; a++) m = fmaxf(m, p[(size_t)a * N]);
    float s = 0.f;
    for (int a = 0; a < N; a++) s += expf(p[(size_t)a * N] - m);
    float inv = 1.f / s;
    for (int a = 0; a < N; a++) p[(size_t)a * N] = expf(p[(size_t)a * N] - m) * inv;
}

// ---------------- chebyshev graph conv + Theta + relu -> sg (in d_out) ----------------
// JT=4: acc = 36 floats/thread — MUST stay in VGPRs (JT=8 + launch_bounds spilled: r5).

constexpr int JT = 4;
constexpr int NJB = (N + JT - 1) / JT;  // 77

__global__ void k_gcnz(const float* __restrict__ x, const float* __restrict__ S,
                       const float* __restrict__ cheb, const float* __restrict__ Theta,
                       float* __restrict__ sg) {
    int blk = blockIdx.x;
    int b = blk / NJB;
    int j0 = (blk % NJB) * JT;
    int tid = threadIdx.x;  // 256

    __shared__ float wl[64][K * JT];  // 3 KB
    __shared__ float zl[K][JT][FT];   // 36 KB

    float acc[K][JT][3];
#pragma unroll
    for (int k = 0; k < K; k++)
#pragma unroll
        for (int jj = 0; jj < JT; jj++)
#pragma unroll
            for (int r = 0; r < 3; r++) acc[k][jj][r] = 0.f;

    const float* xb = x + (size_t)b * N * FT;

    for (int ic = 0; ic < N; ic += 64) {
        for (int l = tid; l < 64 * K * JT; l += 256) {
            int ii = l / (K * JT);
            int m = l % (K * JT);
            int k = m / JT, jj = m % JT;
            int i = ic + ii, j = j0 + jj;
            float w = 0.f;
            if (i < N && j < N)
                w = cheb[((size_t)k * N + i) * N + j] * S[((size_t)b * N + i) * N + j];
            wl[ii][m] = w;
        }
        __syncthreads();
        int imax = min(64, N - ic);
        for (int ii = 0; ii < imax; ii++) {
            float xv[3];
            const float* xr = xb + (size_t)(ic + ii) * FT;
#pragma unroll
            for (int r = 0; r < 3; r++) xv[r] = xr[tid + 256 * r];
#pragma unroll
            for (int k = 0; k < K; k++)
#pragma unroll
                for (int jj = 0; jj < JT; jj++) {
                    float w = wl[ii][k * JT + jj];
#pragma unroll
                    for (int r = 0; r < 3; r++) acc[k][jj][r] += w * xv[r];
                }
        }
        __syncthreads();
    }

    // z -> LDS
#pragma unroll
    for (int k = 0; k < K; k++)
#pragma unroll
        for (int jj = 0; jj < JT; jj++)
#pragma unroll
            for (int r = 0; r < 3; r++) zl[k][jj][tid + 256 * r] = acc[k][jj][r];
    __syncthreads();

    // Theta contraction + relu; each Theta value reused across JT j's
    for (int r = 0; r < 3; r++) {
        int e = tid + 256 * r;  // c*T + t
        int c = e / T;
        int t = e % T;
        float s[JT] = {0.f, 0.f, 0.f, 0.f};
        for (int k = 0; k < K; k++) {
            const float* tp = Theta + (size_t)k * F * C + c;
            const float* zp = &zl[k][0][t];
#pragma unroll 4
            for (int f = 0; f < F; f++) {
                float tv = tp[f * C];
#pragma unroll
                for (int jj = 0; jj < JT; jj++) s[jj] += zp[jj * FT + f * T] * tv;
            }
        }
#pragma unroll
        for (int jj = 0; jj < JT; jj++) {
            int j = j0 + jj;
            if (j < N) sg[((size_t)b * N + j) * FT + e] = fmaxf(s[jj], 0.f);
        }
    }
}

// ---------------- tconv + rconv + relu + LayerNorm (in-place on d_out) ----------------
// v2: RB=4 rows/block (weight traffic /4), transposed+padded LDS tiles so all
// inner reads are conflict-free float4 (r6: scalar ds_read floor ~570us, weight
// refetch ~940MB HBM).

constexpr int RB = 4;
constexpr int PF = 68;  // padded row: 68%8==4 -> per-t bank shift of 4, <=2-way

__global__ void k_rest(const float* __restrict__ x, const float* __restrict__ twT,
                       const float* __restrict__ tb, const float* __restrict__ rw,
                       const float* __restrict__ rb, const float* __restrict__ gamma,
                       const float* __restrict__ beta, float* __restrict__ io) {
    int blk = blockIdx.x;
    size_t bn0 = (size_t)blk * RB;
    int tid = threadIdx.x;  // 256

    __shared__ float xt[RB][T][PF];       // [t][f], 13.1 KB
    __shared__ float sgt[RB][T + 2][PF];  // [t+1][c], rows 0 & T+1 zero, 15.2 KB
    __shared__ float hl[FT];              // [ct*T+t]
    __shared__ float mu[T * RB > 256 ? 1 : T], rstd[T];
    __shared__ float mus[T], rstds[T];
    (void)mu; (void)rstd;

    // zero sgt boundary rows
    for (int l = tid; l < RB * PF; l += 256) {
        int rr = l / PF, c = l % PF;
        sgt[rr][0][c] = 0.f;
        sgt[rr][T + 1][c] = 0.f;
    }
    // stage x and sg (coalesced global reads, scattered LDS writes - one time)
    for (int l = tid; l < RB * FT; l += 256) {
        int rr = l / FT, rem = l % FT;
        int f = rem / T, t = rem % T;  // x/sg layout: [f][t] / [c][t]
        xt[rr][t][f] = x[(bn0 + rr) * FT + rem];
        sgt[rr][t + 1][f] = io[(bn0 + rr) * FT + rem];
    }
    __syncthreads();

    for (int rr = 0; rr < RB; rr++) {
        float hreg[3];
#pragma unroll
        for (int r = 0; r < 3; r++) {
            int e = tid + 256 * r;  // ct*T + t
            int ct = e / T;
            int t = e % T;
            float acc = rb[ct] + tb[ct];
            const float4* rwp = (const float4*)(rw + (size_t)ct * F);
            const float4* xp4 = (const float4*)(&xt[rr][t][0]);
#pragma unroll 4
            for (int q = 0; q < F / 4; q++) {
                float4 w = rwp[q], v = xp4[q];
                acc += w.x * v.x + w.y * v.y + w.z * v.z + w.w * v.w;
            }
#pragma unroll
            for (int dt = 0; dt < 3; dt++) {
                const float4* twp = (const float4*)(twT + ((size_t)dt * CT + ct) * C);
                const float4* sp4 = (const float4*)(&sgt[rr][t + dt][0]);
#pragma unroll 4
                for (int q = 0; q < C / 4; q++) {
                    float4 w = twp[q], v = sp4[q];
                    acc += w.x * v.x + w.y * v.y + w.z * v.z + w.w * v.w;
                }
            }
            hreg[r] = fmaxf(acc, 0.f);
            hl[e] = hreg[r];
        }
        __syncthreads();
        if (tid < T) {
            float m = 0.f;
            for (int ct = 0; ct < CT; ct++) m += hl[ct * T + tid];
            m /= CT;
            float v = 0.f;
            for (int ct = 0; ct < CT; ct++) {
                float d = hl[ct * T + tid] - m;
                v += d * d;
            }
            v /= CT;
            mus[tid] = m;
            rstds[tid] = rsqrtf(v + LN_EPS);
        }
        __syncthreads();
        float* iop = io + (bn0 + rr) * FT;
#pragma unroll
        for (int r = 0; r < 3; r++) {
            int e = tid + 256 * r;
            int ct = e / T;
            int t = e % T;
            iop[e] = (hreg[r] - mus[t]) * rstds[t] * gamma[ct] + beta[ct];
        }
        __syncthreads();  // protect hl/mus before next row overwrites
    }
}

// ---------------- launch ----------------

extern "C" void kernel_launch(void* const* d_in, const int* in_sizes, int n_in,
                              void* d_out, int out_size, void* d_ws, size_t ws_size,
                              hipStream_t stream) {
    const float* x     = (const float*)d_in[0];
    const float* W1    = (const float*)d_in[1];
    const float* W2    = (const float*)d_in[2];
    const float* W3    = (const float*)d_in[3];
    const float* b_s   = (const float*)d_in[4];
    const float* V_s   = (const float*)d_in[5];
    const float* U1    = (const float*)d_in[6];
    const float* U2    = (const float*)d_in[7];
    const float* U3    = (const float*)d_in[8];
    const float* b_e   = (const float*)d_in[9];
    const float* V_e   = (const float*)d_in[10];
    const float* cheb  = (const float*)d_in[11];
    const float* Theta = (const float*)d_in[12];
    const float* tw    = (const float*)d_in[13];
    const float* tb    = (const float*)d_in[14];
    const float* rw    = (const float*)d_in[15];
    const float* rb    = (const float*)d_in[16];
    const float* gam   = (const float*)d_in[17];
    const float* bet   = (const float*)d_in[18];
    float* out = (float*)d_out;

    // workspace (floats): ~29.6 MB (sg lives in d_out)
    float* ws = (float*)d_ws;
    size_t off = 0;
    auto alloc = [&](size_t n) { float* p = ws + off; off += n; return p; };
    float* Sb     = alloc((size_t)B * N * N);
    float* VsT    = alloc((size_t)N * N);
    float* twT    = alloc((size_t)CT * C * 3);
    float* lhs1_e = alloc((size_t)B * T * F);
    float* lhs_e  = alloc((size_t)B * T * N);
    float* rhs_e  = alloc((size_t)B * N * T);
    float* Ebuf   = alloc((size_t)B * T * T);
    float* EW1    = alloc((size_t)B * T);
    float* xw3    = alloc((size_t)B * N * T);
    float* lhs_s  = alloc((size_t)B * N * T);
    float* rhs_s  = alloc((size_t)B * T * N);

    auto g = [](long n) { return dim3((unsigned)((n + 255) / 256)); };

    // temporal attention (k_xdots also precomputes xw3 for spatial attention)
    k_lhs1_e<<<g((long)B * T * F), 256, 0, stream>>>(x, U1, lhs1_e);
    k_xdots<<<g((long)B * N * T), 256, 0, stream>>>(x, U3, W3, rhs_e, xw3);
    k_lhs_e<<<g((long)B * T * N), 256, 0, stream>>>(lhs1_e, U2, lhs_e);
    k_tatt<<<B, 256, 0, stream>>>(lhs_e, rhs_e, b_e, V_e, Ebuf);

    // spatial attention (x_TAt folded in)
    k_EW1<<<g((long)B * T), 256, 0, stream>>>(Ebuf, W1, EW1);
    k_lhs_sf<<<B * N, 64, 0, stream>>>(x, EW1, W2, lhs_s);
    k_rhs_s2<<<g((long)B * T * N), 256, 0, stream>>>(xw3, Ebuf, rhs_s);
    k_transposeVs<<<g((long)N * N), 256, 0, stream>>>(V_s, VsT);
    k_twT<<<g((long)CT * C * 3), 256, 0, stream>>>(tw, twT);
    k_sigS<<<B * NAB, 256, 0, stream>>>(lhs_s, rhs_s, b_s, VsT, Sb);
    k_softmax_S<<<g((long)B * N), 256, 0, stream>>>(Sb);

    // graph conv + Theta + relu -> sg staged in d_out
    k_gcnz<<<B * NJB, 256, 0, stream>>>(x, Sb, cheb, Theta, out);

    // tconv + rconv + relu + LN, in-place on d_out, RB rows per block
    k_rest<<<(B * N) / RB, 256, 0, stream>>>(x, twT, tb, rw, rb, gam, bet, out);
}